// Round 2
// baseline (747.072 us; speedup 1.0000x reference)
//
#include <hip/hip_runtime.h>
#include <hip/hip_bf16.h>

#define NB   512     // batch B
#define S1N  25
#define S2N  10
#define DF   512     // feature dim
#define HID2 512     // 2*HID (concat dim)
#define NHID 256     // HID (GEMM N)
#define NCLS 50

// ---------------- K1: gather fp32 rows, mean per group ----------------------
// grid = ngroups, block = 128; each thread owns 4 consecutive columns (16B)
__global__ void gather_mean_f32(const float* __restrict__ feat,
                                const int* __restrict__ idx,
                                float* __restrict__ out,
                                int gsize, float inv) {
    const int g = blockIdx.x;
    const int col = threadIdx.x * 4;
    float4 acc = make_float4(0.f, 0.f, 0.f, 0.f);
    for (int j = 0; j < gsize; ++j) {
        const int row = idx[g * gsize + j];
        const float4 v = *(const float4*)(feat + (size_t)row * DF + col);
        acc.x += v.x; acc.y += v.y; acc.z += v.z; acc.w += v.w;
    }
    *(float4*)(out + (size_t)g * DF + col) =
        make_float4(acc.x * inv, acc.y * inv, acc.z * inv, acc.w * inv);
}

// ---------------- K3: mean of gsize consecutive fp32 rows per group ---------
__global__ void mean_f32(const float* __restrict__ in, float* __restrict__ out,
                         int gsize, float inv) {
    const int g = blockIdx.x;
    const int col = threadIdx.x * 4;
    float4 acc = make_float4(0.f, 0.f, 0.f, 0.f);
    for (int j = 0; j < gsize; ++j) {
        const float4 v = *(const float4*)(in + ((size_t)g * gsize + j) * DF + col);
        acc.x += v.x; acc.y += v.y; acc.z += v.z; acc.w += v.w;
    }
    *(float4*)(out + (size_t)g * DF + col) =
        make_float4(acc.x * inv, acc.y * inv, acc.z * inv, acc.w * inv);
}

// ---------------- K2: tiled GEMM, C[:, ncol0:ncol0+64*gx] = act(A @ W) ------
// A[M,512] fp32: either gathered via idx from feat, or dense Af. W[512,256]
// fp32 row-major. C fp32 ld=512 written at column offset ncol0.
// 64x64 tile, BK=16, 256 threads, 4x4 microtile. M % 64 == 0 guaranteed.
__global__ void gemm_k512_n256(const float* __restrict__ feat,
                               const int* __restrict__ idx,
                               const float* __restrict__ Af,
                               const float* __restrict__ W,
                               float* __restrict__ C,
                               int ncol0, int relu) {
    __shared__ float As[16][64];
    __shared__ float Ws[16][64];

    const int tid = threadIdx.x;
    const int tx = tid & 15;        // 0..15 -> n quad
    const int ty = tid >> 4;        // 0..15 -> m quad
    const int m0 = blockIdx.y * 64;
    const int nblk = blockIdx.x * 64;

    const int ar = tid >> 2;            // 0..63 (m within tile)
    const int akq = (tid & 3) * 4;      // 0,4,8,12 (k within tile)
    const int wkr = tid >> 4;           // 0..15 (k within tile)
    const int wnq = (tid & 15) * 4;     // n within tile

    float acc[4][4];
#pragma unroll
    for (int i = 0; i < 4; ++i)
#pragma unroll
        for (int j = 0; j < 4; ++j) acc[i][j] = 0.f;

    const float* arow;
    if (idx) arow = feat + (size_t)idx[m0 + ar] * DF;
    else     arow = Af + (size_t)(m0 + ar) * DF;

    for (int k0 = 0; k0 < DF; k0 += 16) {
        const float4 va = *(const float4*)(arow + k0 + akq);
        As[akq + 0][ar] = va.x;
        As[akq + 1][ar] = va.y;
        As[akq + 2][ar] = va.z;
        As[akq + 3][ar] = va.w;

        const float4 vw = *(const float4*)(W + (size_t)(k0 + wkr) * NHID + nblk + wnq);
        Ws[wkr][wnq + 0] = vw.x;
        Ws[wkr][wnq + 1] = vw.y;
        Ws[wkr][wnq + 2] = vw.z;
        Ws[wkr][wnq + 3] = vw.w;
        __syncthreads();
#pragma unroll
        for (int k = 0; k < 16; ++k) {
            float a[4], b[4];
#pragma unroll
            for (int i = 0; i < 4; ++i) a[i] = As[k][ty * 4 + i];
#pragma unroll
            for (int j = 0; j < 4; ++j) b[j] = Ws[k][tx * 4 + j];
#pragma unroll
            for (int i = 0; i < 4; ++i)
#pragma unroll
                for (int j = 0; j < 4; ++j) acc[i][j] += a[i] * b[j];
        }
        __syncthreads();
    }

#pragma unroll
    for (int i = 0; i < 4; ++i) {
        const size_t m = (size_t)(m0 + ty * 4 + i);
#pragma unroll
        for (int j = 0; j < 4; ++j) {
            float v = acc[i][j];
            if (relu) v = fmaxf(v, 0.f);
            C[m * HID2 + ncol0 + nblk + tx * 4 + j] = v;
        }
    }
}

// ---------------- K4: row L2-normalize + logits = norm @ W_pred + b ---------
// grid = 512 rows, block = 256
__global__ void normalize_pred(const float* __restrict__ outb,
                               const float* __restrict__ Wp,
                               const float* __restrict__ bp,
                               float* __restrict__ logits) {
    __shared__ float row[HID2];
    __shared__ float red[256];
    const int r = blockIdx.x;
    const int t = threadIdx.x;

    const float2 v = *(const float2*)(outb + (size_t)r * HID2 + t * 2);
    row[t * 2] = v.x;
    row[t * 2 + 1] = v.y;
    red[t] = v.x * v.x + v.y * v.y;
    __syncthreads();
    for (int s = 128; s > 0; s >>= 1) {
        if (t < s) red[t] += red[t + s];
        __syncthreads();
    }
    const float scale = 1.0f / fmaxf(sqrtf(red[0]), 1e-12f);
    if (t < NCLS) {
        float acc = 0.f;
        for (int k = 0; k < HID2; ++k) acc += row[k] * Wp[k * NCLS + t];
        logits[r * NCLS + t] = acc * scale + bp[t];
    }
}

extern "C" void kernel_launch(void* const* d_in, const int* in_sizes, int n_in,
                              void* d_out, int out_size, void* d_ws, size_t ws_size,
                              hipStream_t stream) {
    const float* feat    = (const float*)d_in[0];
    const float* Wself0  = (const float*)d_in[1];
    const float* Wneigh0 = (const float*)d_in[2];
    const float* Wself1  = (const float*)d_in[3];
    const float* Wneigh1 = (const float*)d_in[4];
    const float* Wpred   = (const float*)d_in[5];
    const float* bpred   = (const float*)d_in[6];
    const int* s0 = (const int*)d_in[7];
    const int* s1 = (const int*)d_in[8];
    const int* s2 = (const int*)d_in[9];

    float* ws = (float*)d_ws;
    float* h2mean = ws;                               // 5120*512
    float* h1mean = h2mean + 5120 * 512;              // 512*512
    float* n1     = h1mean + 512 * 512;               // 5120*512
    float* n0     = n1 + 5120 * 512;                  // 512*512
    float* n1mean = n0 + 512 * 512;                   // 512*512
    float* outb   = n1mean + 512 * 512;               // 512*512

    // neighbor means of raw features
    gather_mean_f32<<<NB * S2N, 128, 0, stream>>>(feat, s2, h2mean, S1N, 1.f / S1N);
    gather_mean_f32<<<NB, 128, 0, stream>>>(feat, s1, h1mean, S2N, 1.f / S2N);

    // layer 0: n1 [5120, 512] and n0 [512, 512], relu
    gemm_k512_n256<<<dim3(4, 80), 256, 0, stream>>>(feat, s1, nullptr, Wself0,  n1, 0,   1);
    gemm_k512_n256<<<dim3(4, 80), 256, 0, stream>>>(nullptr, nullptr, h2mean, Wneigh0, n1, 256, 1);
    gemm_k512_n256<<<dim3(4, 8),  256, 0, stream>>>(feat, s0, nullptr, Wself0,  n0, 0,   1);
    gemm_k512_n256<<<dim3(4, 8),  256, 0, stream>>>(nullptr, nullptr, h1mean, Wneigh0, n0, 256, 1);

    // mean over S2 groups of n1
    mean_f32<<<NB, 128, 0, stream>>>(n1, n1mean, S2N, 1.f / S2N);

    // layer 1: out [512, 512], identity act
    gemm_k512_n256<<<dim3(4, 8), 256, 0, stream>>>(nullptr, nullptr, n0,     Wself1,  outb, 0,   0);
    gemm_k512_n256<<<dim3(4, 8), 256, 0, stream>>>(nullptr, nullptr, n1mean, Wneigh1, outb, 256, 0);

    // normalize + prediction head
    normalize_pred<<<NB, 256, 0, stream>>>(outb, Wpred, bpred, (float*)d_out);
}

// Round 3
// 572.485 us; speedup vs baseline: 1.3050x; 1.3050x over previous
//
#include <hip/hip_runtime.h>

#define DF   512
#define HID2 512
#define NHID 256
#define NCLS 50
#define NB   512

typedef __attribute__((ext_vector_type(8))) short short8;
typedef __attribute__((ext_vector_type(4))) float float4v;

__device__ __forceinline__ float b2f(unsigned short u) {
    union { unsigned int i; float f; } v; v.i = ((unsigned int)u) << 16; return v.f;
}
__device__ __forceinline__ unsigned short f2b(float f) {
    union { float f; unsigned int u; } v; v.f = f;
    unsigned int r = v.u + 0x7FFFu + ((v.u >> 16) & 1u);
    return (unsigned short)(r >> 16);
}

// ---- prep: W [512 k][256 n] fp32 -> Wt [256 n][512 k] bf16, 4 weights ------
// grid (k-tiles=8, n-tiles=4, weight=4), 256 threads, 64x64 tiles
__global__ void prep_weights(const float* __restrict__ W0, const float* __restrict__ W1,
                             const float* __restrict__ W2, const float* __restrict__ W3,
                             unsigned short* __restrict__ Wt) {
    __shared__ unsigned short T[64][66];
    const float* W = (blockIdx.z == 0) ? W0 : (blockIdx.z == 1) ? W1 :
                     (blockIdx.z == 2) ? W2 : W3;
    unsigned short* Out = Wt + (size_t)blockIdx.z * NHID * DF;
    const int k0 = blockIdx.x * 64, n0 = blockIdx.y * 64;
    const int t = threadIdx.x;
#pragma unroll
    for (int p = 0; p < 4; ++p) {
        const int k = p * 16 + (t >> 4);
        const int n = (t & 15) * 4;
        const float4 v = *(const float4*)(W + (size_t)(k0 + k) * NHID + n0 + n);
        T[n + 0][k] = f2b(v.x);
        T[n + 1][k] = f2b(v.y);
        T[n + 2][k] = f2b(v.z);
        T[n + 3][k] = f2b(v.w);
    }
    __syncthreads();
#pragma unroll
    for (int p = 0; p < 4; ++p) {
        const int n = p * 16 + (t >> 4);
        const int k = (t & 15) * 4;
        ushort4 o;
        o.x = T[n][k]; o.y = T[n][k + 1]; o.z = T[n][k + 2]; o.w = T[n][k + 3];
        *(ushort4*)(Out + (size_t)(n0 + n) * DF + k0 + k) = o;
    }
}

// ---- gather rows (fp32 -> bf16): grid = nrows, block = 128 -----------------
__global__ void gather_cvt(const float* __restrict__ feat, const int* __restrict__ idx,
                           unsigned short* __restrict__ out) {
    const int r = blockIdx.x;
    const int col = threadIdx.x * 4;
    const float4 v = *(const float4*)(feat + (size_t)idx[r] * DF + col);
    ushort4 o; o.x = f2b(v.x); o.y = f2b(v.y); o.z = f2b(v.z); o.w = f2b(v.w);
    *(ushort4*)(out + (size_t)r * DF + col) = o;
}

// ---- gather+mean (fp32 -> bf16): grid = ngroups, block = 128 ---------------
template <int GS>
__global__ void gather_mean(const float* __restrict__ feat, const int* __restrict__ idx,
                            unsigned short* __restrict__ out, float inv) {
    const int g = blockIdx.x;
    const int col = threadIdx.x * 4;
    float4 acc = make_float4(0.f, 0.f, 0.f, 0.f);
#pragma unroll
    for (int j = 0; j < GS; ++j) {
        const float4 v = *(const float4*)(feat + (size_t)idx[g * GS + j] * DF + col);
        acc.x += v.x; acc.y += v.y; acc.z += v.z; acc.w += v.w;
    }
    ushort4 o;
    o.x = f2b(acc.x * inv); o.y = f2b(acc.y * inv);
    o.z = f2b(acc.z * inv); o.w = f2b(acc.w * inv);
    *(ushort4*)(out + (size_t)g * DF + col) = o;
}

// ---- group mean of bf16 rows: grid = ngroups, block = 128 ------------------
template <int GS>
__global__ void mean_bf16(const unsigned short* __restrict__ in,
                          unsigned short* __restrict__ out, float inv) {
    const int g = blockIdx.x;
    const int col = threadIdx.x * 4;
    float acc[4] = {0.f, 0.f, 0.f, 0.f};
#pragma unroll
    for (int j = 0; j < GS; ++j) {
        const ushort4 v = *(const ushort4*)(in + ((size_t)g * GS + j) * DF + col);
        acc[0] += b2f(v.x); acc[1] += b2f(v.y); acc[2] += b2f(v.z); acc[3] += b2f(v.w);
    }
    ushort4 o;
    o.x = f2b(acc[0] * inv); o.y = f2b(acc[1] * inv);
    o.z = f2b(acc[2] * inv); o.w = f2b(acc[3] * inv);
    *(ushort4*)(out + (size_t)g * DF + col) = o;
}

// ---- dual MFMA GEMM: C[M,512] = act([A1@W1, A2@W2]) ------------------------
// A1,A2 bf16 [M][512]; W1t,W2t bf16 [256 n][512 k]. Tile 64m x 64n, BK=64,
// 256 threads = 4 waves, each wave does 16m x 64n via 16x16x32 bf16 MFMA.
// grid = (8 n-tiles, M/64). Cout bf16 (cfp32=0) or fp32 (cfp32=1), ld 512.
__global__ __launch_bounds__(256) void gemm_dual_mfma(
        const unsigned short* __restrict__ A1, const unsigned short* __restrict__ A2,
        const unsigned short* __restrict__ W1t, const unsigned short* __restrict__ W2t,
        void* __restrict__ Cout, int relu, int cfp32) {
    __shared__ unsigned short As[64][72];
    __shared__ unsigned short Bs[64][72];
    const int tid = threadIdx.x;
    const int wave = tid >> 6;
    const int lane = tid & 63;
    const int m0 = blockIdx.y * 64;
    const int nb = blockIdx.x * 64;                 // 0..511 global col base
    const unsigned short* A  = (nb < 256) ? A1 : A2;
    const unsigned short* Wt = (nb < 256) ? W1t : W2t;
    const int n0 = nb & 255;                        // col base within the half

    const int sr = tid >> 3;          // 0..31 staging row
    const int sk = (tid & 7) * 8;     // staging k offset (8 bf16 = 16B)

    float4v acc[4];
#pragma unroll
    for (int i = 0; i < 4; ++i) acc[i] = (float4v)(0.f);

    const int am = wave * 16 + (lane & 15);
    const int kq = (lane >> 4) * 8;

    for (int k0 = 0; k0 < DF; k0 += 64) {
        *(uint4*)&As[sr][sk]      = *(const uint4*)(A  + (size_t)(m0 + sr) * DF + k0 + sk);
        *(uint4*)&As[sr + 32][sk] = *(const uint4*)(A  + (size_t)(m0 + sr + 32) * DF + k0 + sk);
        *(uint4*)&Bs[sr][sk]      = *(const uint4*)(Wt + (size_t)(n0 + sr) * DF + k0 + sk);
        *(uint4*)&Bs[sr + 32][sk] = *(const uint4*)(Wt + (size_t)(n0 + sr + 32) * DF + k0 + sk);
        __syncthreads();
#pragma unroll
        for (int ks = 0; ks < 64; ks += 32) {
            const short8 af = *(const short8*)&As[am][ks + kq];
#pragma unroll
            for (int nt = 0; nt < 4; ++nt) {
                const short8 bf = *(const short8*)&Bs[nt * 16 + (lane & 15)][ks + kq];
                acc[nt] = __builtin_amdgcn_mfma_f32_16x16x32_bf16(af, bf, acc[nt], 0, 0, 0);
            }
        }
        __syncthreads();
    }

#pragma unroll
    for (int nt = 0; nt < 4; ++nt) {
        const int gcol = nb + nt * 16 + (lane & 15);
#pragma unroll
        for (int r = 0; r < 4; ++r) {
            const int grow = m0 + wave * 16 + (lane >> 4) * 4 + r;
            float v = acc[nt][r];
            if (relu) v = fmaxf(v, 0.f);
            if (cfp32) ((float*)Cout)[(size_t)grow * HID2 + gcol] = v;
            else ((unsigned short*)Cout)[(size_t)grow * HID2 + gcol] = f2b(v);
        }
    }
}

// ---- normalize + prediction head (fp32): grid = 512, block = 256 -----------
__global__ void normalize_pred(const float* __restrict__ outb,
                               const float* __restrict__ Wp,
                               const float* __restrict__ bp,
                               float* __restrict__ logits) {
    __shared__ float row[HID2];
    __shared__ float red[256];
    const int r = blockIdx.x;
    const int t = threadIdx.x;
    const float2 v = *(const float2*)(outb + (size_t)r * HID2 + t * 2);
    row[t * 2] = v.x;
    row[t * 2 + 1] = v.y;
    red[t] = v.x * v.x + v.y * v.y;
    __syncthreads();
    for (int s = 128; s > 0; s >>= 1) {
        if (t < s) red[t] += red[t + s];
        __syncthreads();
    }
    const float scale = 1.0f / fmaxf(sqrtf(red[0]), 1e-12f);
    if (t < NCLS) {
        float acc = 0.f;
        for (int k = 0; k < HID2; ++k) acc += row[k] * Wp[k * NCLS + t];
        logits[r * NCLS + t] = acc * scale + bp[t];
    }
}

extern "C" void kernel_launch(void* const* d_in, const int* in_sizes, int n_in,
                              void* d_out, int out_size, void* d_ws, size_t ws_size,
                              hipStream_t stream) {
    const float* feat    = (const float*)d_in[0];
    const float* Wself0  = (const float*)d_in[1];
    const float* Wneigh0 = (const float*)d_in[2];
    const float* Wself1  = (const float*)d_in[3];
    const float* Wneigh1 = (const float*)d_in[4];
    const float* Wpred   = (const float*)d_in[5];
    const float* bpred   = (const float*)d_in[6];
    const int* s0 = (const int*)d_in[7];
    const int* s1 = (const int*)d_in[8];
    const int* s2 = (const int*)d_in[9];

    unsigned short* u = (unsigned short*)d_ws;
    unsigned short* h2mean = u;                         // 5120*512
    unsigned short* h1bf   = h2mean + 5120 * 512;       // 5120*512
    unsigned short* n1     = h1bf   + 5120 * 512;       // 5120*512
    unsigned short* h1mean = n1     + 5120 * 512;       // 512*512
    unsigned short* h0bf   = h1mean + 512 * 512;        // 512*512
    unsigned short* n1mean = h0bf   + 512 * 512;        // 512*512
    unsigned short* n0     = n1mean + 512 * 512;        // 512*512
    unsigned short* Wt     = n0     + 512 * 512;        // 4 * 256*512
    float* outb = (float*)(Wt + 4 * NHID * DF);         // 512*512 fp32
    unsigned short* Wt_s0 = Wt;
    unsigned short* Wt_n0 = Wt + 1 * NHID * DF;
    unsigned short* Wt_s1 = Wt + 2 * NHID * DF;
    unsigned short* Wt_n1 = Wt + 3 * NHID * DF;

    prep_weights<<<dim3(8, 4, 4), 256, 0, stream>>>(Wself0, Wneigh0, Wself1, Wneigh1, Wt);
    gather_cvt<<<NB, 128, 0, stream>>>(feat, s0, h0bf);
    gather_cvt<<<NB * 10, 128, 0, stream>>>(feat, s1, h1bf);
    mean_bf16<10><<<NB, 128, 0, stream>>>(h1bf, h1mean, 0.1f);
    gather_mean<25><<<NB * 10, 128, 0, stream>>>(feat, s2, h2mean, 1.f / 25.f);

    gemm_dual_mfma<<<dim3(8, 80), 256, 0, stream>>>(h1bf, h2mean, Wt_s0, Wt_n0, n1, 1, 0);
    mean_bf16<10><<<NB, 128, 0, stream>>>(n1, n1mean, 0.1f);
    gemm_dual_mfma<<<dim3(8, 8), 256, 0, stream>>>(h0bf, h1mean, Wt_s0, Wt_n0, n0, 1, 0);
    gemm_dual_mfma<<<dim3(8, 8), 256, 0, stream>>>(n0, n1mean, Wt_s1, Wt_n1, outb, 0, 1);

    normalize_pred<<<NB, 256, 0, stream>>>(outb, Wpred, bpred, (float*)d_out);
}